// Round 8
// baseline (147.743 us; speedup 1.0000x reference)
//
#include <hip/hip_runtime.h>
#include <hip/hip_fp16.h>

// Idealizer: torsion angles + backbone frames -> atom14 coordinates.
// One thread per residue; each block computes ONE 256-residue tile into an
// LDS row (sidechain fp16 + backbone fp32), then streams out coalesced.
//
// Journal:
// R1: 176 VGPR reg-buffered -> 93 us. R2: forced 64 VGPR -> spill, 159 us.
// R5: LDS out-tile -> clean 82 MB writes, 63 us. R6: 16 waves/CU flat.
// R8: 4 blocks/CU + bank spread -> 57 us (VGPR 84).
// R9/R14: ANY occupancy request >4 waves/EU => allocator squeezes to
//     64/48 VGPR => scratch spill catastrophe. (2,4) is the only safe
//     setting; 16 waves/CU is the ceiling. Live set needs ~110+ VGPRs.
// R10: waves_per_eu(2,4) + early-issue + prefetch + unrolled copyout: 47us.
// R11/R13: AUV restructure q_local = A + c*U + s*V (fp16 U,V), 3 cond
//     chain applies -> ~43 us. 35% VALU cut bought 8%: latency-bound.
// R15: fp16 s_ot + bb staged fp32 in row[15..26], copyout = pure LDS
//     stream -> ~41.7 us. Each work-cut lands at ~1/3 nominal: ~80% stall.
// R16: chain surgery, no algorithm change:
//     (a) neighbor bb (Cm/Nn/CAn) read from LDS rows (written phase 0,
//         before the EXISTING barrier; lanes 0/255 keep global fallback)
//         -> chain head loses ~800cy HBM latency, FETCH -10MB.
//     (b) sc select from 8 packed-half2 REGS via 7-cndmask tree per atom
//         (replaces sincos->LDS write->read round-trip at chain tail).
//     (c) e4/e5/e6 frame loads moved late (free ~36 VGPR mid-phase).
//     Predict kernel 35-38.5us. Tripwire >150: spill -> revert (b).
//     Flat ~135: chain model wrong -> pipeline tiles or roofline.

struct F3 { float x, y, z; };

__device__ __forceinline__ F3 f3sub(F3 a, F3 b) { return {a.x-b.x, a.y-b.y, a.z-b.z}; }
__device__ __forceinline__ F3 f3cross(F3 a, F3 b) {
    return {a.y*b.z - a.z*b.y, a.z*b.x - a.x*b.z, a.x*b.y - a.y*b.x};
}
__device__ __forceinline__ float f3dot(F3 a, F3 b) { return a.x*b.x + a.y*b.y + a.z*b.z; }

__device__ __forceinline__ void dihedral_from(F3 A, F3 B, F3 mid,
                                              float& s, float& c) {
    float x = f3dot(A, B);
    F3 w = f3cross(A, B);
    float y = f3dot(w, mid) * rsqrtf(fmaxf(f3dot(mid, mid), 1e-30f));
    float r2 = x * x + y * y;
    float rinv = rsqrtf(r2);
    bool ok = r2 > 1e-24f;
    s = ok ? y * rinv : 0.0f;   // atan2(0,0)=0 -> angle 0
    c = ok ? x * rinv : 1.0f;
}

// fr_g = dr_g @ Ra(angle): rotation-about-x folded column-wise; trans = dt.
struct Xf12 { float m[9]; float t[3]; };
__device__ __forceinline__ Xf12 mk_fr(float4 r0, float4 r1, float4 r2,
                                      float sA, float cA) {
    Xf12 o;
    o.m[0] = r0.x; o.m[1] = fmaf(cA, r0.y, sA * r0.z); o.m[2] = fmaf(cA, r0.z, -sA * r0.y);
    o.m[3] = r1.x; o.m[4] = fmaf(cA, r1.y, sA * r1.z); o.m[5] = fmaf(cA, r1.z, -sA * r1.y);
    o.m[6] = r2.x; o.m[7] = fmaf(cA, r2.y, sA * r2.z); o.m[8] = fmaf(cA, r2.z, -sA * r2.y);
    o.t[0] = r0.w; o.t[1] = r1.w; o.t[2] = r2.w;
    return o;
}

__device__ __forceinline__ void cond_apply(const Xf12& F, bool cond,
                                           float& qx, float& qy, float& qz) {
    float tx = fmaf(F.m[0], qx, fmaf(F.m[1], qy, fmaf(F.m[2], qz, F.t[0])));
    float ty = fmaf(F.m[3], qx, fmaf(F.m[4], qy, fmaf(F.m[5], qz, F.t[1])));
    float tz = fmaf(F.m[6], qx, fmaf(F.m[7], qy, fmaf(F.m[8], qz, F.t[2])));
    qx = cond ? tx : qx; qy = cond ? ty : qy; qz = cond ? tz : qz;
}

// pack two floats -> one dword of half2; unpack back
__device__ __forceinline__ unsigned pkh(float a, float b) {
    __half2 h = __floats2half2_rn(a, b);
    return *reinterpret_cast<unsigned*>(&h);
}
__device__ __forceinline__ float2 h2fu(unsigned u) {
    __half2 h = *reinterpret_cast<__half2*>(&u);
    return __half22float2(h);
}
__device__ __forceinline__ float u2f(unsigned u) { return __uint_as_float(u); }

// select one of 8 dwords by runtime 3-bit index: 7 cndmask, no LDS
__device__ __forceinline__ unsigned sel8(const unsigned s[8], int g) {
    unsigned a0 = (g & 1) ? s[1] : s[0];
    unsigned a1 = (g & 1) ? s[3] : s[2];
    unsigned a2 = (g & 1) ? s[5] : s[4];
    unsigned a3 = (g & 1) ? s[7] : s[6];
    unsigned b0 = (g & 2) ? a1 : a0;
    unsigned b1 = (g & 2) ? a3 : a2;
    return (g & 4) ? b1 : b0;
}

#define OT_STRIDE 27   // dwords/row: sc half2 [0..14], bb fp32 [15..26];
                       // odd stride -> full 32-bank spread on per-lane rows
#define AUV_AA    84   // dwords/aa: 10 atoms x 8 + 4 pad; atom record =
                       // b128 (A0A1|A2U0|U1U2|V0V1) + b32 (V2|-)

__global__ __launch_bounds__(256)
__attribute__((amdgpu_waves_per_eu(2, 4)))
void idealizer_kernel(
    const int*   __restrict__ aa,       // (n,)
    const float* __restrict__ bb,       // (n,4,3)
    const float* __restrict__ tor,      // (n,4)
    const float* __restrict__ dframes,  // (21,8,4,4)
    const int*   __restrict__ gidx,     // (21,14)
    const float* __restrict__ amask,    // (21,14)
    const float* __restrict__ lit,      // (21,14,3)
    float*       __restrict__ out,      // (n,14,3)
    int n)
{
    __shared__ __align__(8)  unsigned s_ot[256 * OT_STRIDE];  // 27648 B
    __shared__ __align__(16) unsigned s_auv[21 * AUV_AA];     //  7056 B
    __shared__ unsigned s_gpk[21];   // 10 x 3-bit group ids (atoms 4..13)
    __shared__ unsigned s_mbit[21];  // 10 x 1-bit atom mask (atoms 4..13)
    // total 34872 B -> 4 blocks/CU

    const int tid = threadIdx.x;

    // ---- stage per-(aa,atom) constants, fp16-packed ----
    // q_local = A + c*U + s*V  with A = dr[:,0]*lx + dt,
    // U = dr[:,1]*ly + dr[:,2]*lz, V = dr[:,2]*ly - dr[:,1]*lz.
    if (tid < 210) {
        int aai = (tid * 6554) >> 16;        // tid/10, exact for tid<210
        int a   = tid - aai * 10;
        int g   = gidx[aai * 14 + 4 + a];
        const float4* dr4 = (const float4*)dframes + (aai * 8 + g) * 4;
        float4 d0 = dr4[0], d1 = dr4[1], d2 = dr4[2];
        const float* lp = lit + aai * 42 + 12 + a * 3;
        float lx = lp[0], ly = lp[1], lz = lp[2];
        float A0 = fmaf(d0.x, lx, d0.w);
        float A1 = fmaf(d1.x, lx, d1.w);
        float A2 = fmaf(d2.x, lx, d2.w);
        float U0 = fmaf(d0.y, ly, d0.z * lz), V0 = fmaf(d0.z, ly, -d0.y * lz);
        float U1 = fmaf(d1.y, ly, d1.z * lz), V1 = fmaf(d1.z, ly, -d1.y * lz);
        float U2 = fmaf(d2.y, ly, d2.z * lz), V2 = fmaf(d2.z, ly, -d2.y * lz);
        unsigned* w = &s_auv[aai * AUV_AA + a * 8];
        *(uint4*)w = make_uint4(pkh(A0, A1), pkh(A2, U0), pkh(U1, U2), pkh(V0, V1));
        w[4] = pkh(V2, 0.0f);
    }
    if (tid < 21) {
        unsigned gp = 0, mb = 0;
        #pragma unroll
        for (int a = 0; a < 10; a++) {
            gp |= ((unsigned)gidx[tid * 14 + 4 + a]) << (3 * a);
            mb |= (amask[tid * 14 + 4 + a] != 0.0f ? 1u : 0u) << a;
        }
        s_gpk[tid] = gp;
        s_mbit[tid] = mb;
    }

    const int i0 = blockIdx.x * 256;
    const int i  = i0 + tid;
    unsigned* rowd = &s_ot[tid * OT_STRIDE];

    // ---- phase 0: own loads + bb fp32 -> row[15..26] + boundary globals ----
    int aai = 0;
    float4 q0, q1, q2, tv;
    float4 t1g; float t2g;          // lane 0 fallback: C[i-1]
    float4 r0g; float2 r1g;         // lane 255 fallback: N/CA[i+1]
    if (i < n) {
        aai = aa[i];
        const float4* bb4 = (const float4*)bb;
        q0 = bb4[i * 3 + 0];   // N.xyz, CA.x
        q1 = bb4[i * 3 + 1];   // CA.yz, C.xy
        q2 = bb4[i * 3 + 2];   // C.z, O.xyz
        tv = ((const float4*)tor)[i];
        if (tid == 0) {
            int im = (i > 0) ? i - 1 : 0;
            t1g = bb4[im * 3 + 1];
            t2g = bb[im * 12 + 8];
        }
        if (tid == 255) {
            int ip = (i < n - 1) ? i + 1 : 0;
            r0g = bb4[ip * 3 + 0];
            r1g = ((const float2*)bb)[ip * 6 + 2];
        }
        rowd[15] = __float_as_uint(q0.x);
        rowd[16] = __float_as_uint(q0.y);
        rowd[17] = __float_as_uint(q0.z);
        rowd[18] = __float_as_uint(q0.w);
        rowd[19] = __float_as_uint(q1.x);
        rowd[20] = __float_as_uint(q1.y);
        rowd[21] = __float_as_uint(q1.z);
        rowd[22] = __float_as_uint(q1.w);
        rowd[23] = __float_as_uint(q2.x);
        rowd[24] = __float_as_uint(q2.y);
        rowd[25] = __float_as_uint(q2.z);
        rowd[26] = __float_as_uint(q2.w);
    }
    __syncthreads();

    if (i < n) {
        const unsigned gpk  = s_gpk[aai];
        const unsigned mbit = s_mbit[aai];

        F3 Np  = {q0.x, q0.y, q0.z};
        F3 CAp = {q0.w, q1.x, q1.y};
        F3 Cp  = {q1.z, q1.w, q2.x};

        // ---- neighbors from LDS rows (lanes 0/255 use phase-0 globals).
        // Last-block edge (i==n-1, tid<255) reads an unwritten row; the
        // resulting psi/omega are fully overridden below -> safe.
        F3 Cm, Nn, CAn;
        if (tid > 0) {
            const unsigned* rm = rowd - OT_STRIDE;
            Cm = {u2f(rm[21]), u2f(rm[22]), u2f(rm[23])};
        } else {
            Cm = {t1g.z, t1g.w, t2g};
        }
        if (tid < 255) {
            const unsigned* rp = rowd + OT_STRIDE;
            Nn  = {u2f(rp[15]), u2f(rp[16]), u2f(rp[17])};
            CAn = {u2f(rp[18]), u2f(rp[19]), u2f(rp[20])};
        } else {
            Nn  = {r0g.x, r0g.y, r0g.z};
            CAn = {r0g.w, r1g.x, r1g.y};
        }

        // ---- backbone dihedrals via shared bond crosses ----
        F3 u1 = f3sub(Np, Cm);
        F3 u2 = f3sub(CAp, Np);
        F3 u3 = f3sub(Cp, CAp);
        F3 u4 = f3sub(Nn, Cp);
        F3 u5 = f3sub(CAn, Nn);
        F3 c12 = f3cross(u1, u2), c23 = f3cross(u2, u3);
        F3 c34 = f3cross(u3, u4), c45 = f3cross(u4, u5);
        float s_ph, c_ph, s_ps, c_ps, s_om, c_om;
        dihedral_from(c12, c23, u2, s_ph, c_ph);   // phi
        dihedral_from(c23, c34, u3, s_ps, c_ps);   // psi
        dihedral_from(c34, c45, u4, s_om, c_om);   // omega
        if (i == 0)     { s_ph = 0.0f; c_ph = 1.0f; }
        if (i == n - 1) { s_ps = 0.0f; c_ps = 1.0f; s_om = 0.0f; c_om = 1.0f; }

        // ---- backbone frame from reference (N, CA, C) ----
        const float eps = 1e-20f;
        F3 nv = f3sub(Np, CAp);
        F3 cv = f3sub(Cp, CAp);
        float cx = cv.x, cy = cv.y, cz2 = cv.z;
        float d2xy  = cx * cx + cy * cy;
        float inrm  = rsqrtf(eps + d2xy);
        float s1 = -cy * inrm, c1 = cx * inrm;
        float inrm2 = rsqrtf(eps + d2xy + cz2 * cz2);
        float s2v = cz2 * inrm2, c2v = sqrtf(d2xy) * inrm2;
        float Rc00 = c2v * c1,  Rc01 = -c2v * s1, Rc02 = s2v;
        float Rc10 = s1,        Rc11 = c1,        Rc12 = 0.0f;
        float Rc20 = -s2v * c1, Rc21 = s2v * s1,  Rc22 = c2v;
        float n2y = Rc10 * nv.x + Rc11 * nv.y + Rc12 * nv.z;
        float n2z = Rc20 * nv.x + Rc21 * nv.y + Rc22 * nv.z;
        float inrm3 = rsqrtf(eps + n2y * n2y + n2z * n2z);
        float sn = -n2z * inrm3, cn = n2y * inrm3;
        float M10 = cn * Rc10 - sn * Rc20, M11 = cn * Rc11 - sn * Rc21, M12 = cn * Rc12 - sn * Rc22;
        float M20 = sn * Rc10 + cn * Rc20, M21 = sn * Rc11 + cn * Rc21;
        float M22 = sn * Rc12 + cn * Rc22;
        // bb_r = (Rn @ Rc)^T
        float B00 = Rc00, B01 = M10, B02 = M20;
        float B10 = Rc01, B11 = M11, B12 = M21;
        float B20 = Rc02, B21 = M12, B22 = M22;

        // chained-group frame rows (late: hide under sincos, free regs)
        const float4* dfp = (const float4*)dframes + (aai * 32 + 16);
        float4 e40 = dfp[0], e41 = dfp[1],  e42 = dfp[2];
        float4 e50 = dfp[4], e51 = dfp[5],  e52 = dfp[6];
        float4 e60 = dfp[8], e61 = dfp[9],  e62 = dfp[10];

        // ---- per-frame sin/cos: [identity, omega, phi, psi, tor0..3] ----
        float sang[8], cang[8];
        sang[0] = 0.0f; cang[0] = 1.0f;
        sang[1] = s_om; cang[1] = c_om;
        sang[2] = s_ph; cang[2] = c_ph;
        sang[3] = s_ps; cang[3] = c_ps;
        __sincosf(tv.x, &sang[4], &cang[4]);
        __sincosf(tv.y, &sang[5], &cang[5]);
        __sincosf(tv.z, &sang[6], &cang[6]);
        __sincosf(tv.w, &sang[7], &cang[7]);

        // sc packed half2 in REGISTERS (no LDS round-trip on the chain tail)
        unsigned scp[8];
        #pragma unroll
        for (int g8 = 0; g8 < 8; g8++)
            scp[g8] = pkh(sang[g8], cang[g8]);

        // chained-group frames (uniform across the atom loop)
        const Xf12 F4 = mk_fr(e40, e41, e42, sang[4], cang[4]);
        const Xf12 F5 = mk_fr(e50, e51, e52, sang[5], cang[5]);
        const Xf12 F6 = mk_fr(e60, e61, e62, sang[6], cang[6]);

        const unsigned* auv = &s_auv[aai * AUV_AA];
        float px = 0.0f, py = 0.0f, pz = 0.0f;   // even-atom carry
        #pragma unroll
        for (int a = 0; a < 10; a++) {
            int g = (gpk >> (3 * a)) & 7;
            float2 sc = h2fu(sel8(scp, g));      // (sin, cos), 7 cndmask
            uint4 rw = *(const uint4*)(auv + a * 8);
            unsigned rv = auv[a * 8 + 4];
            float2 a01  = h2fu(rw.x);            // A0, A1
            float2 a2u0 = h2fu(rw.y);            // A2, U0
            float2 u12  = h2fu(rw.z);            // U1, U2
            float2 v01  = h2fu(rw.w);            // V0, V1
            float2 v2_  = h2fu(rv);              // V2, -
            // q_local = A + c*U + s*V
            float qx = fmaf(sc.y, a2u0.y, fmaf(sc.x, v01.x, a01.x));
            float qy = fmaf(sc.y, u12.x,  fmaf(sc.x, v01.y, a01.y));
            float qz = fmaf(sc.y, u12.y,  fmaf(sc.x, v2_.x, a2u0.x));
            // chain: apply fr6 if g>=7, fr5 if g>=6, fr4 if g>=5
            cond_apply(F6, g >= 7, qx, qy, qz);
            cond_apply(F5, g >= 6, qx, qy, qz);
            cond_apply(F4, g >= 5, qx, qy, qz);
            // backbone frame + mask
            float mk = ((mbit >> a) & 1u) ? 1.0f : 0.0f;
            float x = mk * fmaf(B00, qx, fmaf(B01, qy, fmaf(B02, qz, CAp.x)));
            float y = mk * fmaf(B10, qx, fmaf(B11, qy, fmaf(B12, qz, CAp.y)));
            float z = mk * fmaf(B20, qx, fmaf(B21, qy, fmaf(B22, qz, CAp.z)));
            // pair-flush to LDS (atoms 2k,2k+1 -> dwords 3k..3k+2)
            if ((a & 1) == 0) {
                px = x; py = y; pz = z;
            } else {
                int base = 3 * (a >> 1);
                rowd[base + 0] = pkh(px, py);
                rowd[base + 1] = pkh(pz, x);
                rowd[base + 2] = pkh(y, z);
            }
        }
    }

    __syncthreads();

    // ---- coalesced copy-out: pure LDS -> global stream ----
    int m = n - i0; if (m > 256) m = 256;
    float2* gout = (float2*)(out + (size_t)i0 * 42);
    if (m == 256) {
        int r = (tid * 24967) >> 19;   // tid/21 (magic, exact for 0..255)
        int j = tid - r * 21;
        #pragma unroll
        for (int k = 0; k < 21; k++) {
            int off = tid + (k << 8);
            int base = r * OT_STRIDE;
            // j<6: backbone fp32 pair at [15+2j]; j>=6: sidechain half2 [j-6]
            unsigned d0 = s_ot[base + ((j < 6) ? (15 + 2 * j) : (j - 6))];
            unsigned d1 = s_ot[base + ((j < 6) ? (16 + 2 * j) : (j - 6))];
            float2 gval = make_float2(__uint_as_float(d0), __uint_as_float(d1));
            float2 lval = h2fu(d0);
            gout[off] = (j < 6) ? gval : lval;
            r += 12; j += 4;                           // 256 = 12*21 + 4
            if (j >= 21) { j -= 21; r += 1; }
        }
    } else {
        const int cnt2 = m * 21;
        int r = tid / 21;
        int j = tid - r * 21;
        for (int off = tid; off < cnt2; off += 256) {
            int base = r * OT_STRIDE;
            unsigned d0 = s_ot[base + ((j < 6) ? (15 + 2 * j) : (j - 6))];
            unsigned d1 = s_ot[base + ((j < 6) ? (16 + 2 * j) : (j - 6))];
            float2 gval = make_float2(__uint_as_float(d0), __uint_as_float(d1));
            float2 lval = h2fu(d0);
            gout[off] = (j < 6) ? gval : lval;
            r += 12; j += 4;
            if (j >= 21) { j -= 21; r += 1; }
        }
    }
}

extern "C" void kernel_launch(void* const* d_in, const int* in_sizes, int n_in,
                              void* d_out, int out_size, void* d_ws, size_t ws_size,
                              hipStream_t stream) {
    const int*   aa  = (const int*)d_in[0];
    const float* bb  = (const float*)d_in[1];
    const float* tor = (const float*)d_in[2];
    const float* df  = (const float*)d_in[3];
    const int*   gi  = (const int*)d_in[4];
    const float* am  = (const float*)d_in[5];
    const float* lp  = (const float*)d_in[6];
    float* outp = (float*)d_out;
    const int n = in_sizes[0];
    const int blocks = (n + 255) / 256;   // one 256-residue tile per block
    idealizer_kernel<<<blocks, 256, 0, stream>>>(aa, bb, tor, df, gi, am, lp, outp, n);
}

// Round 10
// 135.856 us; speedup vs baseline: 1.0875x; 1.0875x over previous
//
#include <hip/hip_runtime.h>
#include <hip/hip_fp16.h>

// Idealizer: torsion angles + backbone frames -> atom14 coordinates.
// One thread per residue; each block computes ONE 256-residue tile into an
// LDS row (sidechain fp16 + backbone fp32), then streams out coalesced.
//
// Journal:
// R1: 176 VGPR reg-buffered -> 93 us. R2: forced 64 VGPR -> spill, 159 us.
// R5: LDS out-tile -> clean 82 MB writes, 63 us.
// R8: 4 blocks/CU + bank spread -> 57 us (VGPR 84).
// R9/R14: ANY occupancy request >4 waves/EU => allocator squeezes to 64/48
//     VGPR => scratch spill. (2,4) is the only safe setting. ALSO (R16):
//     (2,4) lets the allocator take >128 VGPR and silently drop occupancy
//     -> pressure must be managed by construction; kernel counters are
//     invisible below the 51us fill dispatches.
// R10: waves_per_eu(2,4) + early-issue + prefetch + unrolled copyout: 47us.
// R11/R13: AUV restructure q_local = A + c*U + s*V (fp16 U,V), 3 cond
//     chain applies -> ~43 us. 35% VALU cut bought 8%: latency-bound.
// R15: fp16 s_ot + bb staged fp32 in row[15..26], copyout = pure LDS
//     stream -> ~41.7 us (bench 135.8). BEST KNOWN.
// R16: FAILED +12us (bench 147.7). Bundle of (a) neighbor-from-LDS
//     [worthless: neighbor lines are L1-hits of own loads], (b) sc in regs
//     via 7-cndmask tree + (phase-0 restructure) [suspected VGPR growth
//     past an occupancy cliff]. Reverted wholesale.
// R17: R15 + ONE change: all per-thread global loads (aa, bb q0-q2,
//     neighbors t1/t2/r0/r1, tor) issued in PHASE 0 before the staging
//     table work, so staging (~400-700cy of L1 loads + cvt + ds_writes)
//     overlaps the load latency instead of the post-barrier convoy stall.
//     Predict kernel 38-40.5us. Flat => structural plateau; >+2us =>
//     allocator cliff, revert to R15 verbatim.
// R18: R17 never ran — broker infra failure ("container failed twice"),
//     same signature as R12 (which ran fine on resubmit). Kernel audited:
//     no shadowing, bounds unchanged vs R15, no hang paths. Resubmitting
//     R17 UNCHANGED to keep the A/B clean.

struct F3 { float x, y, z; };

__device__ __forceinline__ F3 f3sub(F3 a, F3 b) { return {a.x-b.x, a.y-b.y, a.z-b.z}; }
__device__ __forceinline__ F3 f3cross(F3 a, F3 b) {
    return {a.y*b.z - a.z*b.y, a.z*b.x - a.x*b.z, a.x*b.y - a.y*b.x};
}
__device__ __forceinline__ float f3dot(F3 a, F3 b) { return a.x*b.x + a.y*b.y + a.z*b.z; }

__device__ __forceinline__ void dihedral_from(F3 A, F3 B, F3 mid,
                                              float& s, float& c) {
    float x = f3dot(A, B);
    F3 w = f3cross(A, B);
    float y = f3dot(w, mid) * rsqrtf(fmaxf(f3dot(mid, mid), 1e-30f));
    float r2 = x * x + y * y;
    float rinv = rsqrtf(r2);
    bool ok = r2 > 1e-24f;
    s = ok ? y * rinv : 0.0f;   // atan2(0,0)=0 -> angle 0
    c = ok ? x * rinv : 1.0f;
}

// fr_g = dr_g @ Ra(angle): rotation-about-x folded column-wise; trans = dt.
struct Xf12 { float m[9]; float t[3]; };
__device__ __forceinline__ Xf12 mk_fr(float4 r0, float4 r1, float4 r2,
                                      float sA, float cA) {
    Xf12 o;
    o.m[0] = r0.x; o.m[1] = fmaf(cA, r0.y, sA * r0.z); o.m[2] = fmaf(cA, r0.z, -sA * r0.y);
    o.m[3] = r1.x; o.m[4] = fmaf(cA, r1.y, sA * r1.z); o.m[5] = fmaf(cA, r1.z, -sA * r1.y);
    o.m[6] = r2.x; o.m[7] = fmaf(cA, r2.y, sA * r2.z); o.m[8] = fmaf(cA, r2.z, -sA * r2.y);
    o.t[0] = r0.w; o.t[1] = r1.w; o.t[2] = r2.w;
    return o;
}

__device__ __forceinline__ void cond_apply(const Xf12& F, bool cond,
                                           float& qx, float& qy, float& qz) {
    float tx = fmaf(F.m[0], qx, fmaf(F.m[1], qy, fmaf(F.m[2], qz, F.t[0])));
    float ty = fmaf(F.m[3], qx, fmaf(F.m[4], qy, fmaf(F.m[5], qz, F.t[1])));
    float tz = fmaf(F.m[6], qx, fmaf(F.m[7], qy, fmaf(F.m[8], qz, F.t[2])));
    qx = cond ? tx : qx; qy = cond ? ty : qy; qz = cond ? tz : qz;
}

// pack two floats -> one dword of half2; unpack back
__device__ __forceinline__ unsigned pkh(float a, float b) {
    __half2 h = __floats2half2_rn(a, b);
    return *reinterpret_cast<unsigned*>(&h);
}
__device__ __forceinline__ float2 h2fu(unsigned u) {
    __half2 h = *reinterpret_cast<__half2*>(&u);
    return __half22float2(h);
}

#define OT_STRIDE 27   // dwords/row: v half2 [0..14]; sc fp16 [15..22]
                       // during atom loop, then bb fp32 [15..26]; odd
                       // stride -> full 32-bank spread on per-lane rows
#define AUV_AA    84   // dwords/aa: 10 atoms x 8 + 4 pad; atom record =
                       // b128 (A0A1|A2U0|U1U2|V0V1) + b32 (V2|-)

__global__ __launch_bounds__(256)
__attribute__((amdgpu_waves_per_eu(2, 4)))
void idealizer_kernel(
    const int*   __restrict__ aa,       // (n,)
    const float* __restrict__ bb,       // (n,4,3)
    const float* __restrict__ tor,      // (n,4)
    const float* __restrict__ dframes,  // (21,8,4,4)
    const int*   __restrict__ gidx,     // (21,14)
    const float* __restrict__ amask,    // (21,14)
    const float* __restrict__ lit,      // (21,14,3)
    float*       __restrict__ out,      // (n,14,3)
    int n)
{
    __shared__ __align__(8)  unsigned s_ot[256 * OT_STRIDE];  // 27648 B
    __shared__ __align__(16) unsigned s_auv[21 * AUV_AA];     //  7056 B
    __shared__ unsigned s_gpk[21];   // 10 x 3-bit group ids (atoms 4..13)
    __shared__ unsigned s_mbit[21];  // 10 x 1-bit atom mask (atoms 4..13)
    // total 34872 B -> 4 blocks/CU

    const int tid = threadIdx.x;
    const int i0 = blockIdx.x * 256;
    const int i  = i0 + tid;

    // ---- phase 0: issue ALL per-thread global loads BEFORE staging, so
    // staging's table loads/converts/LDS-writes hide their latency ----
    int aai = 0;
    float4 q0, q1, q2, tv;
    float4 t1; float t2;            // C[i-1]
    float4 r0; float2 r1;           // N[i+1], CA[i+1]
    if (i < n) {
        aai = aa[i];
        const float4* bb4 = (const float4*)bb;
        q0 = bb4[i * 3 + 0];   // N.xyz, CA.x
        q1 = bb4[i * 3 + 1];   // CA.yz, C.xy
        q2 = bb4[i * 3 + 2];   // C.z, O.xyz
        const int im = (i > 0)     ? i - 1 : 0;
        const int ip = (i < n - 1) ? i + 1 : 0;
        t1 = bb4[im * 3 + 1];                 // C[i-1].xy in .z,.w
        t2 = bb[im * 12 + 8];                 // C[i-1].z
        r0 = bb4[ip * 3 + 0];                 // N[i+1], CA[i+1].x
        r1 = ((const float2*)bb)[ip * 6 + 2]; // CA[i+1].yz
        tv = ((const float4*)tor)[i];
    }

    // ---- stage per-(aa,atom) constants, fp16-packed ----
    // q_local = A + c*U + s*V  with A = dr[:,0]*lx + dt,
    // U = dr[:,1]*ly + dr[:,2]*lz, V = dr[:,2]*ly - dr[:,1]*lz.
    if (tid < 210) {
        int saai = (tid * 6554) >> 16;       // tid/10, exact for tid<210
        int a    = tid - saai * 10;
        int g    = gidx[saai * 14 + 4 + a];
        const float4* dr4 = (const float4*)dframes + (saai * 8 + g) * 4;
        float4 d0 = dr4[0], d1 = dr4[1], d2 = dr4[2];
        const float* lp = lit + saai * 42 + 12 + a * 3;
        float lx = lp[0], ly = lp[1], lz = lp[2];
        float A0 = fmaf(d0.x, lx, d0.w);
        float A1 = fmaf(d1.x, lx, d1.w);
        float A2 = fmaf(d2.x, lx, d2.w);
        float U0 = fmaf(d0.y, ly, d0.z * lz), V0 = fmaf(d0.z, ly, -d0.y * lz);
        float U1 = fmaf(d1.y, ly, d1.z * lz), V1 = fmaf(d1.z, ly, -d1.y * lz);
        float U2 = fmaf(d2.y, ly, d2.z * lz), V2 = fmaf(d2.z, ly, -d2.y * lz);
        unsigned* w = &s_auv[saai * AUV_AA + a * 8];
        *(uint4*)w = make_uint4(pkh(A0, A1), pkh(A2, U0), pkh(U1, U2), pkh(V0, V1));
        w[4] = pkh(V2, 0.0f);
    }
    if (tid < 21) {
        unsigned gp = 0, mb = 0;
        #pragma unroll
        for (int a = 0; a < 10; a++) {
            gp |= ((unsigned)gidx[tid * 14 + 4 + a]) << (3 * a);
            mb |= (amask[tid * 14 + 4 + a] != 0.0f ? 1u : 0u) << a;
        }
        s_gpk[tid] = gp;
        s_mbit[tid] = mb;
    }
    __syncthreads();

    unsigned* rowd = &s_ot[tid * OT_STRIDE];
    if (i < n) {
        const unsigned gpk  = s_gpk[aai];
        const unsigned mbit = s_mbit[aai];
        // chained-group frames dr4,dr5,dr6 (tiny table, L1-hot; hidden
        // under the dihedral chain below)
        const float4* dfp = (const float4*)dframes + (aai * 32 + 16);
        float4 e40 = dfp[0], e41 = dfp[1],  e42 = dfp[2];
        float4 e50 = dfp[4], e51 = dfp[5],  e52 = dfp[6];
        float4 e60 = dfp[8], e61 = dfp[9],  e62 = dfp[10];

        F3 Np  = {q0.x, q0.y, q0.z};
        F3 CAp = {q0.w, q1.x, q1.y};
        F3 Cp  = {q1.z, q1.w, q2.x};
        F3 Cm  = {t1.z, t1.w, t2};
        F3 Nn  = {r0.x, r0.y, r0.z};
        F3 CAn = {r0.w, r1.x, r1.y};

        // ---- backbone dihedrals via shared bond crosses ----
        F3 u1 = f3sub(Np, Cm);
        F3 u2 = f3sub(CAp, Np);
        F3 u3 = f3sub(Cp, CAp);
        F3 u4 = f3sub(Nn, Cp);
        F3 u5 = f3sub(CAn, Nn);
        F3 c12 = f3cross(u1, u2), c23 = f3cross(u2, u3);
        F3 c34 = f3cross(u3, u4), c45 = f3cross(u4, u5);
        float s_ph, c_ph, s_ps, c_ps, s_om, c_om;
        dihedral_from(c12, c23, u2, s_ph, c_ph);   // phi
        dihedral_from(c23, c34, u3, s_ps, c_ps);   // psi
        dihedral_from(c34, c45, u4, s_om, c_om);   // omega
        if (i == 0)     { s_ph = 0.0f; c_ph = 1.0f; }
        if (i == n - 1) { s_ps = 0.0f; c_ps = 1.0f; s_om = 0.0f; c_om = 1.0f; }

        // ---- backbone frame from reference (N, CA, C) ----
        const float eps = 1e-20f;
        F3 nv = f3sub(Np, CAp);
        F3 cv = f3sub(Cp, CAp);
        float cx = cv.x, cy = cv.y, cz2 = cv.z;
        float d2xy  = cx * cx + cy * cy;
        float inrm  = rsqrtf(eps + d2xy);
        float s1 = -cy * inrm, c1 = cx * inrm;
        float inrm2 = rsqrtf(eps + d2xy + cz2 * cz2);
        float s2v = cz2 * inrm2, c2v = sqrtf(d2xy) * inrm2;
        float Rc00 = c2v * c1,  Rc01 = -c2v * s1, Rc02 = s2v;
        float Rc10 = s1,        Rc11 = c1,        Rc12 = 0.0f;
        float Rc20 = -s2v * c1, Rc21 = s2v * s1,  Rc22 = c2v;
        float n2y = Rc10 * nv.x + Rc11 * nv.y + Rc12 * nv.z;
        float n2z = Rc20 * nv.x + Rc21 * nv.y + Rc22 * nv.z;
        float inrm3 = rsqrtf(eps + n2y * n2y + n2z * n2z);
        float sn = -n2z * inrm3, cn = n2y * inrm3;
        float M10 = cn * Rc10 - sn * Rc20, M11 = cn * Rc11 - sn * Rc21, M12 = cn * Rc12 - sn * Rc22;
        float M20 = sn * Rc10 + cn * Rc20, M21 = sn * Rc11 + cn * Rc21;
        float M22 = sn * Rc12 + cn * Rc22;
        // bb_r = (Rn @ Rc)^T
        float B00 = Rc00, B01 = M10, B02 = M20;
        float B10 = Rc01, B11 = M11, B12 = M21;
        float B20 = Rc02, B21 = M12, B22 = M22;

        // ---- per-frame sin/cos: [identity, omega, phi, psi, tor0..3] ----
        float sang[8], cang[8];
        sang[0] = 0.0f; cang[0] = 1.0f;
        sang[1] = s_om; cang[1] = c_om;
        sang[2] = s_ph; cang[2] = c_ph;
        sang[3] = s_ps; cang[3] = c_ps;
        __sincosf(tv.x, &sang[4], &cang[4]);
        __sincosf(tv.y, &sang[5], &cang[5]);
        __sincosf(tv.z, &sang[6], &cang[6]);
        __sincosf(tv.w, &sang[7], &cang[7]);

        // sc (fp16 packed) -> row dwords [15..22] (read in atom loop,
        // overwritten by bb AFTER the loop; same-wave DS ops are ordered)
        #pragma unroll
        for (int g8 = 0; g8 < 8; g8++)
            rowd[15 + g8] = pkh(sang[g8], cang[g8]);

        // chained-group frames (uniform across the atom loop)
        const Xf12 F4 = mk_fr(e40, e41, e42, sang[4], cang[4]);
        const Xf12 F5 = mk_fr(e50, e51, e52, sang[5], cang[5]);
        const Xf12 F6 = mk_fr(e60, e61, e62, sang[6], cang[6]);

        const unsigned* auv = &s_auv[aai * AUV_AA];
        float px = 0.0f, py = 0.0f, pz = 0.0f;   // even-atom carry
        #pragma unroll
        for (int a = 0; a < 10; a++) {
            int g = (gpk >> (3 * a)) & 7;
            float2 sc = h2fu(rowd[15 + g]);      // (sin, cos) for group g
            uint4 rw = *(const uint4*)(auv + a * 8);
            unsigned rv = auv[a * 8 + 4];
            float2 a01  = h2fu(rw.x);            // A0, A1
            float2 a2u0 = h2fu(rw.y);            // A2, U0
            float2 u12  = h2fu(rw.z);            // U1, U2
            float2 v01  = h2fu(rw.w);            // V0, V1
            float2 v2_  = h2fu(rv);              // V2, -
            // q_local = A + c*U + s*V
            float qx = fmaf(sc.y, a2u0.y, fmaf(sc.x, v01.x, a01.x));
            float qy = fmaf(sc.y, u12.x,  fmaf(sc.x, v01.y, a01.y));
            float qz = fmaf(sc.y, u12.y,  fmaf(sc.x, v2_.x, a2u0.x));
            // chain: apply fr6 if g>=7, fr5 if g>=6, fr4 if g>=5
            cond_apply(F6, g >= 7, qx, qy, qz);
            cond_apply(F5, g >= 6, qx, qy, qz);
            cond_apply(F4, g >= 5, qx, qy, qz);
            // backbone frame + mask
            float mk = ((mbit >> a) & 1u) ? 1.0f : 0.0f;
            float x = mk * fmaf(B00, qx, fmaf(B01, qy, fmaf(B02, qz, CAp.x)));
            float y = mk * fmaf(B10, qx, fmaf(B11, qy, fmaf(B12, qz, CAp.y)));
            float z = mk * fmaf(B20, qx, fmaf(B21, qy, fmaf(B22, qz, CAp.z)));
            // pair-flush to LDS (atoms 2k,2k+1 -> dwords 3k..3k+2)
            if ((a & 1) == 0) {
                px = x; py = y; pz = z;
            } else {
                int base = 3 * (a >> 1);
                rowd[base + 0] = pkh(px, py);
                rowd[base + 1] = pkh(pz, x);
                rowd[base + 2] = pkh(y, z);
            }
        }

        // ---- backbone fp32 -> row dwords [15..26] (bit-exact passthrough)
        rowd[15] = __float_as_uint(q0.x);
        rowd[16] = __float_as_uint(q0.y);
        rowd[17] = __float_as_uint(q0.z);
        rowd[18] = __float_as_uint(q0.w);
        rowd[19] = __float_as_uint(q1.x);
        rowd[20] = __float_as_uint(q1.y);
        rowd[21] = __float_as_uint(q1.z);
        rowd[22] = __float_as_uint(q1.w);
        rowd[23] = __float_as_uint(q2.x);
        rowd[24] = __float_as_uint(q2.y);
        rowd[25] = __float_as_uint(q2.z);
        rowd[26] = __float_as_uint(q2.w);
    }

    __syncthreads();

    // ---- coalesced copy-out: pure LDS -> global stream ----
    int m = n - i0; if (m > 256) m = 256;
    float2* gout = (float2*)(out + (size_t)i0 * 42);
    if (m == 256) {
        int r = (tid * 24967) >> 19;   // tid/21 (magic, exact for 0..255)
        int j = tid - r * 21;
        #pragma unroll
        for (int k = 0; k < 21; k++) {
            int off = tid + (k << 8);
            int base = r * OT_STRIDE;
            // j<6: backbone fp32 pair at [15+2j]; j>=6: sidechain half2 [j-6]
            unsigned d0 = s_ot[base + ((j < 6) ? (15 + 2 * j) : (j - 6))];
            unsigned d1 = s_ot[base + ((j < 6) ? (16 + 2 * j) : (j - 6))];
            float2 gval = make_float2(__uint_as_float(d0), __uint_as_float(d1));
            float2 lval = h2fu(d0);
            gout[off] = (j < 6) ? gval : lval;
            r += 12; j += 4;                           // 256 = 12*21 + 4
            if (j >= 21) { j -= 21; r += 1; }
        }
    } else {
        const int cnt2 = m * 21;
        int r = tid / 21;
        int j = tid - r * 21;
        for (int off = tid; off < cnt2; off += 256) {
            int base = r * OT_STRIDE;
            unsigned d0 = s_ot[base + ((j < 6) ? (15 + 2 * j) : (j - 6))];
            unsigned d1 = s_ot[base + ((j < 6) ? (16 + 2 * j) : (j - 6))];
            float2 gval = make_float2(__uint_as_float(d0), __uint_as_float(d1));
            float2 lval = h2fu(d0);
            gout[off] = (j < 6) ? gval : lval;
            r += 12; j += 4;
            if (j >= 21) { j -= 21; r += 1; }
        }
    }
}

extern "C" void kernel_launch(void* const* d_in, const int* in_sizes, int n_in,
                              void* d_out, int out_size, void* d_ws, size_t ws_size,
                              hipStream_t stream) {
    const int*   aa  = (const int*)d_in[0];
    const float* bb  = (const float*)d_in[1];
    const float* tor = (const float*)d_in[2];
    const float* df  = (const float*)d_in[3];
    const int*   gi  = (const int*)d_in[4];
    const float* am  = (const float*)d_in[5];
    const float* lp  = (const float*)d_in[6];
    float* outp = (float*)d_out;
    const int n = in_sizes[0];
    const int blocks = (n + 255) / 256;   // one 256-residue tile per block
    idealizer_kernel<<<blocks, 256, 0, stream>>>(aa, bb, tor, df, gi, am, lp, outp, n);
}

// Round 11
// 135.101 us; speedup vs baseline: 1.0936x; 1.0056x over previous
//
#include <hip/hip_runtime.h>
#include <hip/hip_fp16.h>

// Idealizer: torsion angles + backbone frames -> atom14 coordinates.
// One thread per residue; each block computes ONE 256-residue tile into an
// LDS row (sidechain fp16 + backbone fp32); each WAVE streams out its own
// 64 rows with NO barrier (wave-local copyout).
//
// Journal:
// R1: 176 VGPR reg-buffered -> 93 us. R2: forced 64 VGPR -> spill, 159 us.
// R5: LDS out-tile -> clean 82 MB writes, 63 us.
// R8: 4 blocks/CU + bank spread -> 57 us (VGPR 84).
// R9/R14: ANY occupancy request >4 waves/EU => allocator squeezes to 64/48
//     VGPR => scratch spill. (2,4) is the only safe setting. ALSO (R16):
//     (2,4) lets the allocator take >128 VGPR and silently drop occupancy
//     -> pressure must be managed by construction; kernel counters are
//     invisible below the 51us fill dispatches.
// R10: waves_per_eu(2,4) + early-issue + prefetch + unrolled copyout: 47us.
// R11/R13: AUV restructure q_local = A + c*U + s*V (fp16 U,V), 3 cond
//     chain applies -> ~43 us. 35% VALU cut bought 8%: latency-bound.
// R15: fp16 s_ot + bb staged fp32 in row[15..26], copyout = pure LDS
//     stream -> ~41.7 us (bench 135.8). BEST KNOWN.
// R16: FAILED +12us: neighbor-from-LDS (L1-hit fallacy) + reg-pressure.
// R17/R18: phase-0 global-load hoist -> EXACTLY flat (135.855 vs 135.845).
//     Load latency at block start was already hidden. Structural plateau.
// R19: PHASE-LOCK CONVOY theory: per-CU issue ~10us + memory drain ~17us
//     SUM to ~41.7 observed => phases not overlapping. All 4 blocks/CU
//     start together, run identical code, and the block-wide barrier
//     before copyout RE-SYNCS them every tile: all waves compute together
//     (memory idle) then all stream stores together (VALU idle).
//     FIX: wave-local copyout. Each wave's 64 threads computed exactly
//     rows [w*64,w*64+64) — a wave can read its own rows with NO barrier
//     (same-wave DS ops are program-ordered). Delete the final
//     __syncthreads; each wave streams its contiguous 10.5KB region when
//     IT finishes (walk 64=3*21+1). Waves desync -> store drain overlaps
//     sibling compute. Predict kernel 25-33us (bench 119-127); flat =>
//     convoy wrong, declare plateau.

struct F3 { float x, y, z; };

__device__ __forceinline__ F3 f3sub(F3 a, F3 b) { return {a.x-b.x, a.y-b.y, a.z-b.z}; }
__device__ __forceinline__ F3 f3cross(F3 a, F3 b) {
    return {a.y*b.z - a.z*b.y, a.z*b.x - a.x*b.z, a.x*b.y - a.y*b.x};
}
__device__ __forceinline__ float f3dot(F3 a, F3 b) { return a.x*b.x + a.y*b.y + a.z*b.z; }

__device__ __forceinline__ void dihedral_from(F3 A, F3 B, F3 mid,
                                              float& s, float& c) {
    float x = f3dot(A, B);
    F3 w = f3cross(A, B);
    float y = f3dot(w, mid) * rsqrtf(fmaxf(f3dot(mid, mid), 1e-30f));
    float r2 = x * x + y * y;
    float rinv = rsqrtf(r2);
    bool ok = r2 > 1e-24f;
    s = ok ? y * rinv : 0.0f;   // atan2(0,0)=0 -> angle 0
    c = ok ? x * rinv : 1.0f;
}

// fr_g = dr_g @ Ra(angle): rotation-about-x folded column-wise; trans = dt.
struct Xf12 { float m[9]; float t[3]; };
__device__ __forceinline__ Xf12 mk_fr(float4 r0, float4 r1, float4 r2,
                                      float sA, float cA) {
    Xf12 o;
    o.m[0] = r0.x; o.m[1] = fmaf(cA, r0.y, sA * r0.z); o.m[2] = fmaf(cA, r0.z, -sA * r0.y);
    o.m[3] = r1.x; o.m[4] = fmaf(cA, r1.y, sA * r1.z); o.m[5] = fmaf(cA, r1.z, -sA * r1.y);
    o.m[6] = r2.x; o.m[7] = fmaf(cA, r2.y, sA * r2.z); o.m[8] = fmaf(cA, r2.z, -sA * r2.y);
    o.t[0] = r0.w; o.t[1] = r1.w; o.t[2] = r2.w;
    return o;
}

__device__ __forceinline__ void cond_apply(const Xf12& F, bool cond,
                                           float& qx, float& qy, float& qz) {
    float tx = fmaf(F.m[0], qx, fmaf(F.m[1], qy, fmaf(F.m[2], qz, F.t[0])));
    float ty = fmaf(F.m[3], qx, fmaf(F.m[4], qy, fmaf(F.m[5], qz, F.t[1])));
    float tz = fmaf(F.m[6], qx, fmaf(F.m[7], qy, fmaf(F.m[8], qz, F.t[2])));
    qx = cond ? tx : qx; qy = cond ? ty : qy; qz = cond ? tz : qz;
}

// pack two floats -> one dword of half2; unpack back
__device__ __forceinline__ unsigned pkh(float a, float b) {
    __half2 h = __floats2half2_rn(a, b);
    return *reinterpret_cast<unsigned*>(&h);
}
__device__ __forceinline__ float2 h2fu(unsigned u) {
    __half2 h = *reinterpret_cast<__half2*>(&u);
    return __half22float2(h);
}

#define OT_STRIDE 27   // dwords/row: v half2 [0..14]; sc fp16 [15..22]
                       // during atom loop, then bb fp32 [15..26]; odd
                       // stride -> full 32-bank spread on per-lane rows
#define AUV_AA    84   // dwords/aa: 10 atoms x 8 + 4 pad; atom record =
                       // b128 (A0A1|A2U0|U1U2|V0V1) + b32 (V2|-)

__global__ __launch_bounds__(256)
__attribute__((amdgpu_waves_per_eu(2, 4)))
void idealizer_kernel(
    const int*   __restrict__ aa,       // (n,)
    const float* __restrict__ bb,       // (n,4,3)
    const float* __restrict__ tor,      // (n,4)
    const float* __restrict__ dframes,  // (21,8,4,4)
    const int*   __restrict__ gidx,     // (21,14)
    const float* __restrict__ amask,    // (21,14)
    const float* __restrict__ lit,      // (21,14,3)
    float*       __restrict__ out,      // (n,14,3)
    int n)
{
    __shared__ __align__(8)  unsigned s_ot[256 * OT_STRIDE];  // 27648 B
    __shared__ __align__(16) unsigned s_auv[21 * AUV_AA];     //  7056 B
    __shared__ unsigned s_gpk[21];   // 10 x 3-bit group ids (atoms 4..13)
    __shared__ unsigned s_mbit[21];  // 10 x 1-bit atom mask (atoms 4..13)
    // total 34872 B -> 4 blocks/CU

    const int tid = threadIdx.x;
    const int i0 = blockIdx.x * 256;
    const int i  = i0 + tid;

    // ---- phase 0: issue ALL per-thread global loads BEFORE staging, so
    // staging's table loads/converts/LDS-writes hide their latency ----
    int aai = 0;
    float4 q0, q1, q2, tv;
    float4 t1; float t2;            // C[i-1]
    float4 r0; float2 r1;           // N[i+1], CA[i+1]
    if (i < n) {
        aai = aa[i];
        const float4* bb4 = (const float4*)bb;
        q0 = bb4[i * 3 + 0];   // N.xyz, CA.x
        q1 = bb4[i * 3 + 1];   // CA.yz, C.xy
        q2 = bb4[i * 3 + 2];   // C.z, O.xyz
        const int im = (i > 0)     ? i - 1 : 0;
        const int ip = (i < n - 1) ? i + 1 : 0;
        t1 = bb4[im * 3 + 1];                 // C[i-1].xy in .z,.w
        t2 = bb[im * 12 + 8];                 // C[i-1].z
        r0 = bb4[ip * 3 + 0];                 // N[i+1], CA[i+1].x
        r1 = ((const float2*)bb)[ip * 6 + 2]; // CA[i+1].yz
        tv = ((const float4*)tor)[i];
    }

    // ---- stage per-(aa,atom) constants, fp16-packed ----
    // q_local = A + c*U + s*V  with A = dr[:,0]*lx + dt,
    // U = dr[:,1]*ly + dr[:,2]*lz, V = dr[:,2]*ly - dr[:,1]*lz.
    if (tid < 210) {
        int saai = (tid * 6554) >> 16;       // tid/10, exact for tid<210
        int a    = tid - saai * 10;
        int g    = gidx[saai * 14 + 4 + a];
        const float4* dr4 = (const float4*)dframes + (saai * 8 + g) * 4;
        float4 d0 = dr4[0], d1 = dr4[1], d2 = dr4[2];
        const float* lp = lit + saai * 42 + 12 + a * 3;
        float lx = lp[0], ly = lp[1], lz = lp[2];
        float A0 = fmaf(d0.x, lx, d0.w);
        float A1 = fmaf(d1.x, lx, d1.w);
        float A2 = fmaf(d2.x, lx, d2.w);
        float U0 = fmaf(d0.y, ly, d0.z * lz), V0 = fmaf(d0.z, ly, -d0.y * lz);
        float U1 = fmaf(d1.y, ly, d1.z * lz), V1 = fmaf(d1.z, ly, -d1.y * lz);
        float U2 = fmaf(d2.y, ly, d2.z * lz), V2 = fmaf(d2.z, ly, -d2.y * lz);
        unsigned* w = &s_auv[saai * AUV_AA + a * 8];
        *(uint4*)w = make_uint4(pkh(A0, A1), pkh(A2, U0), pkh(U1, U2), pkh(V0, V1));
        w[4] = pkh(V2, 0.0f);
    }
    if (tid < 21) {
        unsigned gp = 0, mb = 0;
        #pragma unroll
        for (int a = 0; a < 10; a++) {
            gp |= ((unsigned)gidx[tid * 14 + 4 + a]) << (3 * a);
            mb |= (amask[tid * 14 + 4 + a] != 0.0f ? 1u : 0u) << a;
        }
        s_gpk[tid] = gp;
        s_mbit[tid] = mb;
    }
    __syncthreads();

    unsigned* rowd = &s_ot[tid * OT_STRIDE];
    if (i < n) {
        const unsigned gpk  = s_gpk[aai];
        const unsigned mbit = s_mbit[aai];
        // chained-group frames dr4,dr5,dr6 (tiny table, L1-hot; hidden
        // under the dihedral chain below)
        const float4* dfp = (const float4*)dframes + (aai * 32 + 16);
        float4 e40 = dfp[0], e41 = dfp[1],  e42 = dfp[2];
        float4 e50 = dfp[4], e51 = dfp[5],  e52 = dfp[6];
        float4 e60 = dfp[8], e61 = dfp[9],  e62 = dfp[10];

        F3 Np  = {q0.x, q0.y, q0.z};
        F3 CAp = {q0.w, q1.x, q1.y};
        F3 Cp  = {q1.z, q1.w, q2.x};
        F3 Cm  = {t1.z, t1.w, t2};
        F3 Nn  = {r0.x, r0.y, r0.z};
        F3 CAn = {r0.w, r1.x, r1.y};

        // ---- backbone dihedrals via shared bond crosses ----
        F3 u1 = f3sub(Np, Cm);
        F3 u2 = f3sub(CAp, Np);
        F3 u3 = f3sub(Cp, CAp);
        F3 u4 = f3sub(Nn, Cp);
        F3 u5 = f3sub(CAn, Nn);
        F3 c12 = f3cross(u1, u2), c23 = f3cross(u2, u3);
        F3 c34 = f3cross(u3, u4), c45 = f3cross(u4, u5);
        float s_ph, c_ph, s_ps, c_ps, s_om, c_om;
        dihedral_from(c12, c23, u2, s_ph, c_ph);   // phi
        dihedral_from(c23, c34, u3, s_ps, c_ps);   // psi
        dihedral_from(c34, c45, u4, s_om, c_om);   // omega
        if (i == 0)     { s_ph = 0.0f; c_ph = 1.0f; }
        if (i == n - 1) { s_ps = 0.0f; c_ps = 1.0f; s_om = 0.0f; c_om = 1.0f; }

        // ---- backbone frame from reference (N, CA, C) ----
        const float eps = 1e-20f;
        F3 nv = f3sub(Np, CAp);
        F3 cv = f3sub(Cp, CAp);
        float cx = cv.x, cy = cv.y, cz2 = cv.z;
        float d2xy  = cx * cx + cy * cy;
        float inrm  = rsqrtf(eps + d2xy);
        float s1 = -cy * inrm, c1 = cx * inrm;
        float inrm2 = rsqrtf(eps + d2xy + cz2 * cz2);
        float s2v = cz2 * inrm2, c2v = sqrtf(d2xy) * inrm2;
        float Rc00 = c2v * c1,  Rc01 = -c2v * s1, Rc02 = s2v;
        float Rc10 = s1,        Rc11 = c1,        Rc12 = 0.0f;
        float Rc20 = -s2v * c1, Rc21 = s2v * s1,  Rc22 = c2v;
        float n2y = Rc10 * nv.x + Rc11 * nv.y + Rc12 * nv.z;
        float n2z = Rc20 * nv.x + Rc21 * nv.y + Rc22 * nv.z;
        float inrm3 = rsqrtf(eps + n2y * n2y + n2z * n2z);
        float sn = -n2z * inrm3, cn = n2y * inrm3;
        float M10 = cn * Rc10 - sn * Rc20, M11 = cn * Rc11 - sn * Rc21, M12 = cn * Rc12 - sn * Rc22;
        float M20 = sn * Rc10 + cn * Rc20, M21 = sn * Rc11 + cn * Rc21;
        float M22 = sn * Rc12 + cn * Rc22;
        // bb_r = (Rn @ Rc)^T
        float B00 = Rc00, B01 = M10, B02 = M20;
        float B10 = Rc01, B11 = M11, B12 = M21;
        float B20 = Rc02, B21 = M12, B22 = M22;

        // ---- per-frame sin/cos: [identity, omega, phi, psi, tor0..3] ----
        float sang[8], cang[8];
        sang[0] = 0.0f; cang[0] = 1.0f;
        sang[1] = s_om; cang[1] = c_om;
        sang[2] = s_ph; cang[2] = c_ph;
        sang[3] = s_ps; cang[3] = c_ps;
        __sincosf(tv.x, &sang[4], &cang[4]);
        __sincosf(tv.y, &sang[5], &cang[5]);
        __sincosf(tv.z, &sang[6], &cang[6]);
        __sincosf(tv.w, &sang[7], &cang[7]);

        // sc (fp16 packed) -> row dwords [15..22] (read in atom loop,
        // overwritten by bb AFTER the loop; same-wave DS ops are ordered)
        #pragma unroll
        for (int g8 = 0; g8 < 8; g8++)
            rowd[15 + g8] = pkh(sang[g8], cang[g8]);

        // chained-group frames (uniform across the atom loop)
        const Xf12 F4 = mk_fr(e40, e41, e42, sang[4], cang[4]);
        const Xf12 F5 = mk_fr(e50, e51, e52, sang[5], cang[5]);
        const Xf12 F6 = mk_fr(e60, e61, e62, sang[6], cang[6]);

        const unsigned* auv = &s_auv[aai * AUV_AA];
        float px = 0.0f, py = 0.0f, pz = 0.0f;   // even-atom carry
        #pragma unroll
        for (int a = 0; a < 10; a++) {
            int g = (gpk >> (3 * a)) & 7;
            float2 sc = h2fu(rowd[15 + g]);      // (sin, cos) for group g
            uint4 rw = *(const uint4*)(auv + a * 8);
            unsigned rv = auv[a * 8 + 4];
            float2 a01  = h2fu(rw.x);            // A0, A1
            float2 a2u0 = h2fu(rw.y);            // A2, U0
            float2 u12  = h2fu(rw.z);            // U1, U2
            float2 v01  = h2fu(rw.w);            // V0, V1
            float2 v2_  = h2fu(rv);              // V2, -
            // q_local = A + c*U + s*V
            float qx = fmaf(sc.y, a2u0.y, fmaf(sc.x, v01.x, a01.x));
            float qy = fmaf(sc.y, u12.x,  fmaf(sc.x, v01.y, a01.y));
            float qz = fmaf(sc.y, u12.y,  fmaf(sc.x, v2_.x, a2u0.x));
            // chain: apply fr6 if g>=7, fr5 if g>=6, fr4 if g>=5
            cond_apply(F6, g >= 7, qx, qy, qz);
            cond_apply(F5, g >= 6, qx, qy, qz);
            cond_apply(F4, g >= 5, qx, qy, qz);
            // backbone frame + mask
            float mk = ((mbit >> a) & 1u) ? 1.0f : 0.0f;
            float x = mk * fmaf(B00, qx, fmaf(B01, qy, fmaf(B02, qz, CAp.x)));
            float y = mk * fmaf(B10, qx, fmaf(B11, qy, fmaf(B12, qz, CAp.y)));
            float z = mk * fmaf(B20, qx, fmaf(B21, qy, fmaf(B22, qz, CAp.z)));
            // pair-flush to LDS (atoms 2k,2k+1 -> dwords 3k..3k+2)
            if ((a & 1) == 0) {
                px = x; py = y; pz = z;
            } else {
                int base = 3 * (a >> 1);
                rowd[base + 0] = pkh(px, py);
                rowd[base + 1] = pkh(pz, x);
                rowd[base + 2] = pkh(y, z);
            }
        }

        // ---- backbone fp32 -> row dwords [15..26] (bit-exact passthrough)
        rowd[15] = __float_as_uint(q0.x);
        rowd[16] = __float_as_uint(q0.y);
        rowd[17] = __float_as_uint(q0.z);
        rowd[18] = __float_as_uint(q0.w);
        rowd[19] = __float_as_uint(q1.x);
        rowd[20] = __float_as_uint(q1.y);
        rowd[21] = __float_as_uint(q1.z);
        rowd[22] = __float_as_uint(q1.w);
        rowd[23] = __float_as_uint(q2.x);
        rowd[24] = __float_as_uint(q2.y);
        rowd[25] = __float_as_uint(q2.z);
        rowd[26] = __float_as_uint(q2.w);
    }

    // ---- wave-local copy-out: NO barrier. This wave's 64 threads wrote
    // exactly rows [w*64, w*64+64); same-wave DS ops are program-ordered,
    // so the reads below see them. Waves desync -> store drain overlaps
    // sibling waves' compute (convoy broken).
    const int w    = tid >> 6;
    const int lane = tid & 63;
    const int rbase = w << 6;              // first local row of this wave
    int valid = n - i0 - rbase; if (valid > 64) valid = 64;
    if (valid > 0) {
        float2* gout = (float2*)(out + (size_t)(i0 + rbase) * 42);
        if (valid == 64) {
            int r = (lane * 24967) >> 19;  // lane/21 (magic, exact 0..255)
            int j = lane - r * 21;
            #pragma unroll
            for (int k = 0; k < 21; k++) {
                int off = lane + (k << 6);
                int base = (rbase + r) * OT_STRIDE;
                // j<6: bb fp32 pair at [15+2j]; j>=6: sidechain half2 [j-6]
                unsigned d0 = s_ot[base + ((j < 6) ? (15 + 2 * j) : (j - 6))];
                unsigned d1 = s_ot[base + ((j < 6) ? (16 + 2 * j) : (j - 6))];
                float2 gval = make_float2(__uint_as_float(d0), __uint_as_float(d1));
                float2 lval = h2fu(d0);
                gout[off] = (j < 6) ? gval : lval;
                r += 3; j += 1;            // 64 = 3*21 + 1
                if (j >= 21) { j -= 21; r += 1; }
            }
        } else {
            const int cnt2 = valid * 21;
            int r = lane / 21;
            int j = lane - r * 21;
            for (int off = lane; off < cnt2; off += 64) {
                int base = (rbase + r) * OT_STRIDE;
                unsigned d0 = s_ot[base + ((j < 6) ? (15 + 2 * j) : (j - 6))];
                unsigned d1 = s_ot[base + ((j < 6) ? (16 + 2 * j) : (j - 6))];
                float2 gval = make_float2(__uint_as_float(d0), __uint_as_float(d1));
                float2 lval = h2fu(d0);
                gout[off] = (j < 6) ? gval : lval;
                r += 3; j += 1;
                if (j >= 21) { j -= 21; r += 1; }
            }
        }
    }
}

extern "C" void kernel_launch(void* const* d_in, const int* in_sizes, int n_in,
                              void* d_out, int out_size, void* d_ws, size_t ws_size,
                              hipStream_t stream) {
    const int*   aa  = (const int*)d_in[0];
    const float* bb  = (const float*)d_in[1];
    const float* tor = (const float*)d_in[2];
    const float* df  = (const float*)d_in[3];
    const int*   gi  = (const int*)d_in[4];
    const float* am  = (const float*)d_in[5];
    const float* lp  = (const float*)d_in[6];
    float* outp = (float*)d_out;
    const int n = in_sizes[0];
    const int blocks = (n + 255) / 256;   // one 256-residue tile per block
    idealizer_kernel<<<blocks, 256, 0, stream>>>(aa, bb, tor, df, gi, am, lp, outp, n);
}